// Round 15
// baseline (254.887 us; speedup 1.0000x reference)
//
#include <hip/hip_runtime.h>

typedef __attribute__((ext_vector_type(8))) __bf16 bf16x8;
typedef __attribute__((ext_vector_type(4))) float f32x4;
typedef __attribute__((ext_vector_type(16))) float f32x16;
typedef __attribute__((ext_vector_type(4))) unsigned int u32x4;
typedef unsigned short u16;
typedef unsigned int u32;

__device__ __forceinline__ u16 f2bf(float f) {
  __bf16 h = (__bf16)f;
  return *(u16*)&h;
}
__device__ __forceinline__ float bf2f(u16 h) {
  return __uint_as_float(((u32)h) << 16);
}
__device__ __forceinline__ u32 pack2(float lo, float hi) {
  return (u32)f2bf(lo) | ((u32)f2bf(hi) << 16);
}
__device__ __forceinline__ f32x4 mfma16(bf16x8 a, bf16x8 b, f32x4 c) {
  return __builtin_amdgcn_mfma_f32_16x16x32_bf16(a, b, c, 0, 0, 0);
}
__device__ __forceinline__ f32x16 mfma32(bf16x8 a, bf16x8 b, f32x16 c) {
  return __builtin_amdgcn_mfma_f32_32x32x16_bf16(a, b, c, 0, 0, 0);
}
__device__ __forceinline__ void gl16(const void* g, void* l) {
  __builtin_amdgcn_global_load_lds(
      (const __attribute__((address_space(1))) void*)g,
      (__attribute__((address_space(3))) void*)l, 16, 0, 0);
}

// ---------------- converts ----------------
__global__ void cvt_to_bf16(const float* __restrict__ src, u16* __restrict__ dst, int n) {
  const int i = (blockIdx.x * 256 + threadIdx.x) * 4;
  if (i + 3 < n) {
    const float4 v = *(const float4*)(src + i);
    ushort4 o; o.x = f2bf(v.x); o.y = f2bf(v.y); o.z = f2bf(v.z); o.w = f2bf(v.w);
    *(ushort4*)(dst + i) = o;
  }
}

// fused prep: wqkv^T (0..767), wproj^T (768..1023), mirrored bias table (1024..1087).
__global__ __launch_bounds__(256) void prep_misc(
    const float* __restrict__ w_qkv, const float* __restrict__ w_proj,
    const float* __restrict__ rel_tab,
    u16* __restrict__ wT, u16* __restrict__ wpT, u16* __restrict__ mtab)
{
  __shared__ float tile[32][33];
  const int b = blockIdx.x;
  const int tid = threadIdx.x;
  if (b < 1024) {
    const float* src; u16* dst; int C, c0, r0;
    if (b < 768) { src = w_qkv; dst = wT; C = 1536; c0 = (b % 48) * 32; r0 = (b / 48) * 32; }
    else { const int bb = b - 768; src = w_proj; dst = wpT; C = 512; c0 = (bb % 16) * 32; r0 = (bb / 16) * 32; }
    const int tx = tid & 31, ty = tid >> 5;
    for (int i = ty; i < 32; i += 8)
      tile[i][tx] = src[(size_t)(r0 + i) * C + c0 + tx];
    __syncthreads();
    for (int i = ty; i < 32; i += 8)
      dst[(size_t)(c0 + i) * 512 + r0 + tx] = f2bf(tile[tx][i]);
  } else {
    const int e = (b - 1024) * 256 + tid;
    if (e <= 16128) {
      const float* r0 = rel_tab + (size_t)e * 8;
      const float* r1 = rel_tab + (size_t)(16128 - e) * 8;
      const float4 a0 = *(const float4*)r0, a1 = *(const float4*)(r0 + 4);
      const float4 b0 = *(const float4*)r1, b1 = *(const float4*)(r1 + 4);
      u16* d = mtab + (size_t)e * 16;
      ushort4 w0 = {f2bf(a0.x), f2bf(a0.y), f2bf(a0.z), f2bf(a0.w)};
      ushort4 w1 = {f2bf(a1.x), f2bf(a1.y), f2bf(a1.z), f2bf(a1.w)};
      ushort4 w2 = {f2bf(b0.x), f2bf(b0.y), f2bf(b0.z), f2bf(b0.w)};
      ushort4 w3 = {f2bf(b1.x), f2bf(b1.y), f2bf(b1.z), f2bf(b1.w)};
      *(ushort4*)(d)      = w0;
      *(ushort4*)(d + 4)  = w1;
      *(ushort4*)(d + 8)  = w2;
      *(ushort4*)(d + 12) = w3;
    }
  }
}

// ---------------- bias pre-pass v2: mirror-paired gather over 64x64 tile-pairs ----
__global__ __launch_bounds__(512) void bias_prep(
    const int* __restrict__ ids_keep, const u16* __restrict__ mtab,
    u16* __restrict__ pre)
{
  __shared__ u16 TB[4096 * 8];   // 64KB transposed-tile staging
  __shared__ int ca[64], cb[64];

  const int bid = blockIdx.x;
  const int b = bid / 136;
  int rr = bid % 136;
  int ta = 0;
  while (rr >= 16 - ta) { rr -= 16 - ta; ++ta; }
  const int tb = ta + rr;
  const int tid = threadIdx.x;

  if (tid < 64) {
    const int id = ids_keep[b * 1024 + ta * 64 + tid];
    ca[tid] = (id >> 6) * 127 + (id & 63);
  } else if (tid < 128) {
    const int id = ids_keep[b * 1024 + tb * 64 + (tid - 64)];
    cb[tid - 64] = (id >> 6) * 127 + (id & 63);
  }
  __syncthreads();

  const size_t preB = (size_t)b * 32 * 16 * 2048 * 8;

  if (ta == tb) {
#pragma unroll
    for (int k = 0; k < 8; ++k) {
      const int p = k * 512 + tid;
      const int i = p >> 6, j = p & 63;
      const int idx = ca[i] - cb[j] + 8064;
      const ushort4 v = *(const ushort4*)(mtab + (size_t)idx * 16);
      const int g32 = 2 * ta + (i >> 5);
      const int pc = (i & 31) * 64 + (j ^ ((i & 15) << 2));
      *(ushort4*)(pre + preB + (((size_t)(g32 * 16 + ta)) * 2048 + pc) * 8) = v;
    }
    return;
  }

#pragma unroll
  for (int k = 0; k < 8; ++k) {
    const int p = k * 512 + tid;
    const int i = p >> 6, j = p & 63;        // n = 64ta+i, m = 64tb+j
    const int idx = ca[i] - cb[j] + 8064;
    const ushort4 lo = *(const ushort4*)(mtab + (size_t)idx * 16);      // bias(n,m)
    const ushort4 hi = *(const ushort4*)(mtab + (size_t)idx * 16 + 8);  // bias(m,n)
    const int g32 = 2 * ta + (i >> 5);
    const int pc = (i & 31) * 64 + (j ^ ((i & 15) << 2));
    *(ushort4*)(pre + preB + (((size_t)(g32 * 16 + tb)) * 2048 + pc) * 8) = lo;
    *(ushort4*)(&TB[(j * 64 + (i ^ (j & 7))) * 8]) = hi;
  }
  __syncthreads();
#pragma unroll
  for (int q = 0; q < 8; ++q) {
    const int c = q * 512 + tid;
    const int j = c >> 6, i = c & 63;
    const ushort4 v = *(const ushort4*)(&TB[(j * 64 + (i ^ (j & 7))) * 8]);
    const int g32 = 2 * tb + (j >> 5);
    const int pc = (j & 31) * 64 + (i ^ ((j & 15) << 2));
    *(ushort4*)(pre + preB + (((size_t)(g32 * 16 + ta)) * 2048 + pc) * 8) = v;
  }
}

// ---------------- GEMM: C[MxN] = A[Mx512] * Bt[Nx512]^T, K=512 ----------------
template<int MODE>
__global__ __launch_bounds__(256, 2) void gemm_bt(
    const u16* __restrict__ A, const u16* __restrict__ Bt,
    u16* __restrict__ out0, u16* __restrict__ out1,
    float* __restrict__ fout, const float* __restrict__ bias)
{
  __shared__ u16 As[128][32];
  __shared__ u16 Bs[128][32];
  const int tid = threadIdx.x;
  const int w = tid >> 6, l = tid & 63;
  const int lr = l & 15, lg = l >> 4;
  const int wr = w >> 1, wc = w & 1;
  const int m0 = blockIdx.y * 128, n0 = blockIdx.x * 128;
  const int sl = (lr >> 1) & 3;
  const int cA = lg ^ sl;

  f32x4 acc[4][4] = {};

  for (int k0 = 0; k0 < 512; k0 += 32) {
#pragma unroll
    for (int it = 0; it < 2; ++it) {
      const int ch = it * 256 + tid;
      const int row = ch >> 2, cslot = ch & 3;
      const int csrc = cslot ^ ((row >> 1) & 3);
      gl16(A  + (size_t)(m0 + row) * 512 + k0 + csrc * 8, (u16*)As + ch * 8);
      gl16(Bt + (size_t)(n0 + row) * 512 + k0 + csrc * 8, (u16*)Bs + ch * 8);
    }
    __syncthreads();
    bf16x8 af[4], bfr[4];
#pragma unroll
    for (int mi = 0; mi < 4; ++mi)
      af[mi] = *(const bf16x8*)&As[wr * 64 + mi * 16 + lr][cA * 8];
#pragma unroll
    for (int nj = 0; nj < 4; ++nj)
      bfr[nj] = *(const bf16x8*)&Bs[wc * 64 + nj * 16 + lr][cA * 8];
#pragma unroll
    for (int mi = 0; mi < 4; ++mi)
#pragma unroll
      for (int nj = 0; nj < 4; ++nj)
        acc[mi][nj] = mfma16(af[mi], bfr[nj], acc[mi][nj]);
    __syncthreads();
  }

#pragma unroll
  for (int mi = 0; mi < 4; ++mi)
#pragma unroll
    for (int nj = 0; nj < 4; ++nj) {
      const int i0 = m0 + wr * 64 + mi * 16 + lg * 4;
      const int j  = n0 + wc * 64 + nj * 16 + lr;
      if (MODE == 0) {
        const int bb = j >> 10, n = j & 1023;
        const bool isQ = i0 < 512;
        const int f = isQ ? i0 : i0 - 512;
        const int h = f >> 6, d0 = f & 63;
        const float scl = isQ ? 0.125f : 1.0f;
        u16* dst = isQ ? out0 : out1;
        const size_t off = ((size_t)(bb * 8 + h) << 16) +
            ((((n >> 5) * 4 + (d0 >> 4)) * 2 + ((d0 >> 3) & 1)) << 8) +
            ((n & 31) << 3) + (d0 & 7);
        ushort4 o;
        o.x = f2bf(acc[mi][nj][0] * scl); o.y = f2bf(acc[mi][nj][1] * scl);
        o.z = f2bf(acc[mi][nj][2] * scl); o.w = f2bf(acc[mi][nj][3] * scl);
        *(ushort4*)(dst + off) = o;
      } else if (MODE == 1) {
        const int bb = i0 >> 10, m = i0 & 1023;
        const int h = j >> 6, d = j & 63;
        const size_t off = ((size_t)(bb * 8 + h) << 16) +
            ((((m >> 6) * 4 + ((m >> 4) & 3)) * 2 + ((m >> 2) & 1)) << 9) +
            (d << 3) + (((m >> 3) & 1) << 2);
        ushort4 o;
        o.x = f2bf(acc[mi][nj][0]); o.y = f2bf(acc[mi][nj][1]);
        o.z = f2bf(acc[mi][nj][2]); o.w = f2bf(acc[mi][nj][3]);
        *(ushort4*)(out0 + off) = o;
      } else {
        const float4 bp = *(const float4*)(bias + i0);
        float4 o;
        o.x = acc[mi][nj][0] + bp.x; o.y = acc[mi][nj][1] + bp.y;
        o.z = acc[mi][nj][2] + bp.z; o.w = acc[mi][nj][3] + bp.w;
        *(float4*)(fout + (size_t)j * 512 + i0) = o;
      }
    }
}

// ---------------- flash attention (32x32 swapped-operand, sigma-PV) ----------------
// grid 512: bb=bid&7 (XCD chunk), r2=bid>>3: hp=r2&1, g32=r2>>1.
// 256 thr = 4 waves = 4 heads, 16 KV tiles, single pass.
// K register-double-buffered (ping-pong kA/kB) so the QK MFMA never waits on a
// same-iteration load; bias stream stays 1-deep prefetched; V issued early in-body.
// setprio(1) around MFMA clusters (T5: independent blocks per CU, m191 regime).
__global__ __launch_bounds__(256, 3) void flash_attn(
    const u16* __restrict__ Qs, const u16* __restrict__ Ks,
    const u16* __restrict__ Vs, const u16* __restrict__ pre,
    u16* __restrict__ attn_out)
{
  __shared__ u16 BiF[2][4][2056];

  const int bid = blockIdx.x;
  const int bb = bid & 7;
  const int r2 = bid >> 3;
  const int hp = r2 & 1;
  const int g32 = r2 >> 1;
  const int tid = threadIdx.x;
  const int w = tid >> 6;
  const int l = tid & 63, l31 = l & 31, hi5 = l >> 5;
  const int h = hp * 4 + w;

  const size_t hb = (size_t)(bb * 8 + h) << 16;
  const u16* preb = pre + (size_t)(bb * 32 + g32) * 16 * 2048 * 8 + hp * 4;

  f32x16 acc0 = {}, acc1 = {};
  float lsum = 0.f;

  bf16x8 qf[4];
#pragma unroll
  for (int dch = 0; dch < 4; ++dch)
    qf[dch] = *(const bf16x8*)(Qs + hb + (size_t)(((g32 * 4 + dch) * 2 + hi5) * 256 + l31 * 8));

  auto gather_issue = [&](int t, ushort4 (&gv)[8]) {
    const u16* p = preb + (size_t)t * 2048 * 8;
#pragma unroll
    for (int i = 0; i < 8; ++i)
      gv[i] = *(const ushort4*)(p + (size_t)(i * 256 + tid) * 8);
  };
  auto gather_commit = [&](int buf, ushort4 (&gv)[8]) {
#pragma unroll
    for (int i = 0; i < 8; ++i) {
      const int pc = i * 256 + tid;
      BiF[buf][0][pc] = gv[i].x;
      BiF[buf][1][pc] = gv[i].y;
      BiF[buf][2][pc] = gv[i].z;
      BiF[buf][3][pc] = gv[i].w;
    }
  };
  auto kload = [&](int t, bf16x8 (&kf)[8]) {
#pragma unroll
    for (int u = 0; u < 2; ++u)
#pragma unroll
      for (int dch = 0; dch < 4; ++dch)
        kf[u * 4 + dch] = *(const bf16x8*)(Ks + hb +
            (size_t)((((2 * t + u) * 4 + dch) * 2 + hi5) * 256 + l31 * 8));
  };
  auto vload = [&](int t, bf16x8 (&vf)[8]) {
#pragma unroll
    for (int cp = 0; cp < 4; ++cp)
#pragma unroll
      for (int dc = 0; dc < 2; ++dc)
        vf[cp * 2 + dc] = *(const bf16x8*)(Vs + hb +
            (size_t)(((t * 4 + cp) * 2 + hi5) * 512 + (dc * 32 + l31) * 8));
  };

  // prologue: K(0) + bias(0)
  bf16x8 kA[8], kB[8];
  {
    ushort4 g0[8];
    gather_issue(0, g0);
    kload(0, kA);
    gather_commit(0, g0);
  }
  __syncthreads();

  auto body = [&](int t, bool pf, bf16x8 (&kC)[8], bf16x8 (&kN)[8]) {
    ushort4 gv[8];
    if (pf) {
      kload(t + 1, kN);           // K(t+1): consumed at next body's QK
      gather_issue(t + 1, gv);    // bias(t+1)
    }
    bf16x8 vC[8];
    vload(t, vC);                 // V(t): consumed after softmax (~400cy later)
    const int buf = t & 1;
    const int rsw = (l31 & 15) << 2;
    const u16* bip = &BiF[buf][w][l31 * 64];

    u32 pk[2][4][2];
#pragma unroll
    for (int u = 0; u < 2; ++u) {
      f32x16 s = {};
      __builtin_amdgcn_s_setprio(1);
      s = mfma32(kC[u * 4 + 0], qf[0], s);
      s = mfma32(kC[u * 4 + 1], qf[1], s);
      s = mfma32(kC[u * 4 + 2], qf[2], s);
      s = mfma32(kC[u * 4 + 3], qf[3], s);
      __builtin_amdgcn_s_setprio(0);
#pragma unroll
      for (int a = 0; a < 4; ++a) {
        const int colb = (u * 32 + a * 8 + hi5 * 4) ^ rsw;
        const ushort4 bv = *(const ushort4*)(bip + colb);
        float p0 = __expf(s[a * 4 + 0] + bf2f(bv.x));
        float p1 = __expf(s[a * 4 + 1] + bf2f(bv.y));
        float p2 = __expf(s[a * 4 + 2] + bf2f(bv.z));
        float p3 = __expf(s[a * 4 + 3] + bf2f(bv.w));
        lsum += (p0 + p1) + (p2 + p3);
        pk[u][a][0] = pack2(p0, p1);
        pk[u][a][1] = pack2(p2, p3);
      }
    }

    if (pf) gather_commit(buf ^ 1, gv);
    __syncthreads();

    __builtin_amdgcn_s_setprio(1);
#pragma unroll
    for (int cp = 0; cp < 4; ++cp) {
      const int u = cp >> 1, cc = cp & 1;
      union { u32x4 u4; bf16x8 v; } pb;
      pb.u4 = (u32x4){pk[u][2 * cc][0], pk[u][2 * cc][1],
                      pk[u][2 * cc + 1][0], pk[u][2 * cc + 1][1]};
      acc0 = mfma32(vC[cp * 2 + 0], pb.v, acc0);
      acc1 = mfma32(vC[cp * 2 + 1], pb.v, acc1);
    }
    __builtin_amdgcn_s_setprio(0);
  };

  for (int tt = 0; tt < 16; tt += 2) {
    body(tt,     tt < 15,     kA, kB);
    body(tt + 1, tt + 1 < 15, kB, kA);
  }

  lsum += __shfl_xor(lsum, 32);
  const float inv = 1.0f / lsum;
  const int nglob = bb * 1024 + g32 * 32 + l31;
#pragma unroll
  for (int dc = 0; dc < 2; ++dc) {
    const f32x16& av = dc ? acc1 : acc0;
#pragma unroll
    for (int rq = 0; rq < 4; ++rq) {
      const int d = dc * 32 + rq * 8 + hi5 * 4;
      ushort4 o;
      o.x = f2bf(av[rq * 4 + 0] * inv);
      o.y = f2bf(av[rq * 4 + 1] * inv);
      o.z = f2bf(av[rq * 4 + 2] * inv);
      o.w = f2bf(av[rq * 4 + 3] * inv);
      *(ushort4*)(attn_out + (size_t)nglob * 512 + h * 64 + d) = o;
    }
  }
}

// ---------------- launch ----------------
extern "C" void kernel_launch(void* const* d_in, const int* in_sizes, int n_in,
                              void* d_out, int out_size, void* d_ws, size_t ws_size,
                              hipStream_t stream) {
  const float* x        = (const float*)d_in[0];
  const int*   ids      = (const int*)d_in[1];
  const float* w_qkv    = (const float*)d_in[2];
  const float* w_proj   = (const float*)d_in[3];
  const float* b_proj   = (const float*)d_in[4];
  const float* rel_tab  = (const float*)d_in[5];
  float* out = (float*)d_out;

  char* ws = (char*)d_ws;
  u16* xb   = (u16*)(ws);              // 8192x512 bf16; later reused as attn_out
  u16* wT   = (u16*)(ws + 8388608);    // 1536x512 bf16
  u16* wpT  = (u16*)(ws + 9961472);    // 512x512 bf16
  u16* Qsw  = (u16*)(ws + 10485760);   // swizzled Q (8MB); mtab lives here BEFORE gemm0
  u16* Ksw  = (u16*)(ws + 18874368);   // swizzled K (8MB)
  u16* Vsw  = (u16*)(ws + 27262976);   // sigma-swizzled V (8MB)
  u16* pre  = (u16*)(ws + 35913728);   // bias tiles [8][32][16][2048][8h] bf16 (134MB)
  u16* mtab = Qsw;                     // mirrored table (516KB), dead once gemm0 runs
  u16* attn = xb;

  cvt_to_bf16<<<4096, 256, 0, stream>>>(x, xb, 8 * 1024 * 512);
  prep_misc<<<1088, 256, 0, stream>>>(w_qkv, w_proj, rel_tab, wT, wpT, mtab);
  bias_prep<<<1088, 512, 0, stream>>>(ids, mtab, pre);

  gemm_bt<0><<<dim3(64, 8), 256, 0, stream>>>(wT, xb, Qsw, Ksw, nullptr, nullptr);
  gemm_bt<1><<<dim3(4, 64), 256, 0, stream>>>(xb, wT + 1024 * 512, Vsw, nullptr, nullptr, nullptr);

  flash_attn<<<dim3(512), 256, 0, stream>>>(Qsw, Ksw, Vsw, pre, attn);

  gemm_bt<2><<<dim3(64, 4), 256, 0, stream>>>(wpT, attn, nullptr, nullptr, out, b_proj);
}

// Round 16
// 124.615 us; speedup vs baseline: 2.0454x; 2.0454x over previous
//
#include <hip/hip_runtime.h>

typedef __attribute__((ext_vector_type(8))) __bf16 bf16x8;
typedef __attribute__((ext_vector_type(4))) float f32x4;
typedef __attribute__((ext_vector_type(16))) float f32x16;
typedef __attribute__((ext_vector_type(4))) unsigned int u32x4;
typedef unsigned short u16;
typedef unsigned int u32;

__device__ __forceinline__ u16 f2bf(float f) {
  __bf16 h = (__bf16)f;
  return *(u16*)&h;
}
__device__ __forceinline__ float bf2f(u16 h) {
  return __uint_as_float(((u32)h) << 16);
}
__device__ __forceinline__ u32 pack2(float lo, float hi) {
  return (u32)f2bf(lo) | ((u32)f2bf(hi) << 16);
}
__device__ __forceinline__ f32x4 mfma16(bf16x8 a, bf16x8 b, f32x4 c) {
  return __builtin_amdgcn_mfma_f32_16x16x32_bf16(a, b, c, 0, 0, 0);
}
__device__ __forceinline__ f32x16 mfma32(bf16x8 a, bf16x8 b, f32x16 c) {
  return __builtin_amdgcn_mfma_f32_32x32x16_bf16(a, b, c, 0, 0, 0);
}
__device__ __forceinline__ void gl16(const void* g, void* l) {
  __builtin_amdgcn_global_load_lds(
      (const __attribute__((address_space(1))) void*)g,
      (__attribute__((address_space(3))) void*)l, 16, 0, 0);
}

// ---------------- converts ----------------
__global__ void cvt_to_bf16(const float* __restrict__ src, u16* __restrict__ dst, int n) {
  const int i = (blockIdx.x * 256 + threadIdx.x) * 4;
  if (i + 3 < n) {
    const float4 v = *(const float4*)(src + i);
    ushort4 o; o.x = f2bf(v.x); o.y = f2bf(v.y); o.z = f2bf(v.z); o.w = f2bf(v.w);
    *(ushort4*)(dst + i) = o;
  }
}

// fused prep: wqkv^T (blocks 0..767), wproj^T (768..1023), rel_table cvt (1024..1150)
__global__ __launch_bounds__(256) void prep_misc(
    const float* __restrict__ w_qkv, const float* __restrict__ w_proj,
    const float* __restrict__ rel_tab,
    u16* __restrict__ wT, u16* __restrict__ wpT, u16* __restrict__ tabb)
{
  __shared__ float tile[32][33];
  const int b = blockIdx.x;
  const int tid = threadIdx.x;
  if (b < 1024) {
    const float* src; u16* dst; int C, c0, r0;
    if (b < 768) { src = w_qkv; dst = wT; C = 1536; c0 = (b % 48) * 32; r0 = (b / 48) * 32; }
    else { const int bb = b - 768; src = w_proj; dst = wpT; C = 512; c0 = (bb % 16) * 32; r0 = (bb / 16) * 32; }
    const int tx = tid & 31, ty = tid >> 5;
    for (int i = ty; i < 32; i += 8)
      tile[i][tx] = src[(size_t)(r0 + i) * C + c0 + tx];
    __syncthreads();
    for (int i = ty; i < 32; i += 8)
      dst[(size_t)(c0 + i) * 512 + r0 + tx] = f2bf(tile[tx][i]);
  } else {
    const int i = ((b - 1024) * 256 + tid) * 4;
    if (i + 3 < 16131 * 8) {
      const float4 v = *(const float4*)(rel_tab + i);
      ushort4 o; o.x = f2bf(v.x); o.y = f2bf(v.y); o.z = f2bf(v.z); o.w = f2bf(v.w);
      *(ushort4*)(tabb + i) = o;
    }
  }
}

// ---------------- GEMM: C[MxN] = A[Mx512] * Bt[Nx512]^T, K=512 ----------------
template<int MODE>
__global__ __launch_bounds__(256, 2) void gemm_bt(
    const u16* __restrict__ A, const u16* __restrict__ Bt,
    u16* __restrict__ out0, u16* __restrict__ out1,
    float* __restrict__ fout, const float* __restrict__ bias)
{
  __shared__ u16 As[128][32];
  __shared__ u16 Bs[128][32];
  const int tid = threadIdx.x;
  const int w = tid >> 6, l = tid & 63;
  const int lr = l & 15, lg = l >> 4;
  const int wr = w >> 1, wc = w & 1;
  const int m0 = blockIdx.y * 128, n0 = blockIdx.x * 128;
  const int sl = (lr >> 1) & 3;
  const int cA = lg ^ sl;

  f32x4 acc[4][4] = {};

  for (int k0 = 0; k0 < 512; k0 += 32) {
#pragma unroll
    for (int it = 0; it < 2; ++it) {
      const int ch = it * 256 + tid;
      const int row = ch >> 2, cslot = ch & 3;
      const int csrc = cslot ^ ((row >> 1) & 3);
      gl16(A  + (size_t)(m0 + row) * 512 + k0 + csrc * 8, (u16*)As + ch * 8);
      gl16(Bt + (size_t)(n0 + row) * 512 + k0 + csrc * 8, (u16*)Bs + ch * 8);
    }
    __syncthreads();
    bf16x8 af[4], bfr[4];
#pragma unroll
    for (int mi = 0; mi < 4; ++mi)
      af[mi] = *(const bf16x8*)&As[wr * 64 + mi * 16 + lr][cA * 8];
#pragma unroll
    for (int nj = 0; nj < 4; ++nj)
      bfr[nj] = *(const bf16x8*)&Bs[wc * 64 + nj * 16 + lr][cA * 8];
#pragma unroll
    for (int mi = 0; mi < 4; ++mi)
#pragma unroll
      for (int nj = 0; nj < 4; ++nj)
        acc[mi][nj] = mfma16(af[mi], bfr[nj], acc[mi][nj]);
    __syncthreads();
  }

#pragma unroll
  for (int mi = 0; mi < 4; ++mi)
#pragma unroll
    for (int nj = 0; nj < 4; ++nj) {
      const int i0 = m0 + wr * 64 + mi * 16 + lg * 4;
      const int j  = n0 + wc * 64 + nj * 16 + lr;
      if (MODE == 0) {
        const int bb = j >> 10, n = j & 1023;
        const bool isQ = i0 < 512;
        const int f = isQ ? i0 : i0 - 512;
        const int h = f >> 6, d0 = f & 63;
        const float scl = isQ ? 0.125f : 1.0f;
        u16* dst = isQ ? out0 : out1;
        const size_t off = ((size_t)(bb * 8 + h) << 16) +
            ((((n >> 5) * 4 + (d0 >> 4)) * 2 + ((d0 >> 3) & 1)) << 8) +
            ((n & 31) << 3) + (d0 & 7);
        ushort4 o;
        o.x = f2bf(acc[mi][nj][0] * scl); o.y = f2bf(acc[mi][nj][1] * scl);
        o.z = f2bf(acc[mi][nj][2] * scl); o.w = f2bf(acc[mi][nj][3] * scl);
        *(ushort4*)(dst + off) = o;
      } else if (MODE == 1) {
        const int bb = i0 >> 10, m = i0 & 1023;
        const int h = j >> 6, d = j & 63;
        const size_t off = ((size_t)(bb * 8 + h) << 16) +
            ((((m >> 6) * 4 + ((m >> 4) & 3)) * 2 + ((m >> 2) & 1)) << 9) +
            (d << 3) + (((m >> 3) & 1) << 2);
        ushort4 o;
        o.x = f2bf(acc[mi][nj][0]); o.y = f2bf(acc[mi][nj][1]);
        o.z = f2bf(acc[mi][nj][2]); o.w = f2bf(acc[mi][nj][3]);
        *(ushort4*)(out0 + off) = o;
      } else {
        const float4 bp = *(const float4*)(bias + i0);
        float4 o;
        o.x = acc[mi][nj][0] + bp.x; o.y = acc[mi][nj][1] + bp.y;
        o.z = acc[mi][nj][2] + bp.z; o.w = acc[mi][nj][3] + bp.w;
        *(float4*)(fout + (size_t)j * 512 + i0) = o;
      }
    }
}

// ---------------- flash attention (32x32 swapped-operand, sigma-PV, merged heads) --
// grid 512: bb=bid&7 (XCD chunk), r2=bid>>3: kvh=r2&1, g32=r2>>1.
// 512 thr = 8 waves = ALL 8 heads -> each table row fetched ONCE (16B, 8 heads):
// scattered requests halve vs the 4-head/hp-split version (16.8M -> 8.4M).
// KV-split retained (8 tiles/block, linear-combining partials; combine pass follows).
// Register diet for the (512,4) 128-reg cap: K loaded 4-frags-per-u, V 2-per-cp.
__global__ __launch_bounds__(512, 4) void flash_attn(
    const u16* __restrict__ Qs, const u16* __restrict__ Ks,
    const u16* __restrict__ Vs, const int* __restrict__ ids_keep,
    const u16* __restrict__ tab_bf,
    float* __restrict__ pO, float* __restrict__ pL)
{
  __shared__ u16 BiF[2][8][2056];
  __shared__ int cs[1024];

  const int bid = blockIdx.x;
  const int bb = bid & 7;
  const int r2 = bid >> 3;
  const int kvh = r2 & 1;
  const int g32 = r2 >> 1;
  const int tid = threadIdx.x;
  const int w = tid >> 6;               // head 0..7
  const int l = tid & 63, l31 = l & 31, hi5 = l >> 5;
  const int t0 = kvh * 8;

  {
    const int id0 = ids_keep[bb * 1024 + tid];
    const int id1 = ids_keep[bb * 1024 + tid + 512];
    cs[tid]       = (id0 >> 6) * 127 + (id0 & 63);
    cs[tid + 512] = (id1 >> 6) * 127 + (id1 & 63);
  }

  const size_t hb = (size_t)(bb * 8 + w) << 16;

  f32x16 acc0 = {}, acc1 = {};
  float lsum = 0.f;

  __syncthreads();

  bf16x8 qf[4];
#pragma unroll
  for (int dch = 0; dch < 4; ++dch)
    qf[dch] = *(const bf16x8*)(Qs + hb + (size_t)(((g32 * 4 + dch) * 2 + hi5) * 256 + l31 * 8));

  // 2048 pairs/iter, 4 per thread; one int4 (16B) = all 8 heads of the pair
  auto gather_issue = [&](int t, int4 (&gv)[4]) {
    const int mb = t * 64;
#pragma unroll
    for (int i = 0; i < 4; ++i) {
      const int pair = i * 512 + tid;
      const int pn = pair >> 6, pm = pair & 63;
      const int idx = cs[g32 * 32 + pn] - cs[mb + pm] + 8064;
      gv[i] = *(const int4*)(tab_bf + (size_t)idx * 8);
    }
  };
  auto gather_commit = [&](int buf, int4 (&gv)[4]) {
#pragma unroll
    for (int i = 0; i < 4; ++i) {
      const int pair = i * 512 + tid;
      const int pn = pair >> 6, pm = pair & 63;
      const int pc = pn * 64 + (pm ^ ((pn & 15) << 2));
      union { int4 v; u16 s[8]; } uu;
      uu.v = gv[i];
#pragma unroll
      for (int hh = 0; hh < 8; ++hh)
        BiF[buf][hh][pc] = uu.s[hh];
    }
  };

  // prologue: bias(t0)
  {
    int4 g0[4];
    gather_issue(t0, g0);
    gather_commit(0, g0);
  }
  __syncthreads();

  auto body = [&](int t, bool pf) {
    int4 gv[4];
    if (pf) gather_issue(t + 1, gv);
    const int buf = t & 1;
    const int rsw = (l31 & 15) << 2;
    const u16* bip = &BiF[buf][w][l31 * 64];

    u32 pk[2][4][2];
#pragma unroll
    for (int u = 0; u < 2; ++u) {
      bf16x8 kc[4];
#pragma unroll
      for (int dch = 0; dch < 4; ++dch)
        kc[dch] = *(const bf16x8*)(Ks + hb +
            (size_t)((((2 * t + u) * 4 + dch) * 2 + hi5) * 256 + l31 * 8));
      f32x16 s = {};
      s = mfma32(kc[0], qf[0], s);
      s = mfma32(kc[1], qf[1], s);
      s = mfma32(kc[2], qf[2], s);
      s = mfma32(kc[3], qf[3], s);
#pragma unroll
      for (int a = 0; a < 4; ++a) {
        const int colb = (u * 32 + a * 8 + hi5 * 4) ^ rsw;
        const ushort4 bv = *(const ushort4*)(bip + colb);
        float p0 = __expf(s[a * 4 + 0] + bf2f(bv.x));
        float p1 = __expf(s[a * 4 + 1] + bf2f(bv.y));
        float p2 = __expf(s[a * 4 + 2] + bf2f(bv.z));
        float p3 = __expf(s[a * 4 + 3] + bf2f(bv.w));
        lsum += (p0 + p1) + (p2 + p3);
        pk[u][a][0] = pack2(p0, p1);
        pk[u][a][1] = pack2(p2, p3);
      }
    }

    if (pf) gather_commit(buf ^ 1, gv);
    __syncthreads();

#pragma unroll
    for (int cp = 0; cp < 4; ++cp) {
      bf16x8 vc[2];
#pragma unroll
      for (int dc = 0; dc < 2; ++dc)
        vc[dc] = *(const bf16x8*)(Vs + hb +
            (size_t)(((t * 4 + cp) * 2 + hi5) * 512 + (dc * 32 + l31) * 8));
      const int u = cp >> 1, cc = cp & 1;
      union { u32x4 u4; bf16x8 v; } pb;
      pb.u4 = (u32x4){pk[u][2 * cc][0], pk[u][2 * cc][1],
                      pk[u][2 * cc + 1][0], pk[u][2 * cc + 1][1]};
      acc0 = mfma32(vc[0], pb.v, acc0);
      acc1 = mfma32(vc[1], pb.v, acc1);
    }
  };

  for (int tr = 0; tr < 8; ++tr)
    body(t0 + tr, tr < 7);

  lsum += __shfl_xor(lsum, 32);
  const size_t nrow = (size_t)(bb * 8 + w) * 1024 + g32 * 32 + l31;
  if (hi5 == 0) pL[nrow * 2 + kvh] = lsum;
#pragma unroll
  for (int dc = 0; dc < 2; ++dc) {
    const f32x16& av = dc ? acc1 : acc0;
#pragma unroll
    for (int rq = 0; rq < 4; ++rq) {
      const int d = dc * 32 + rq * 8 + hi5 * 4;
      float4 o = {av[rq * 4 + 0], av[rq * 4 + 1], av[rq * 4 + 2], av[rq * 4 + 3]};
      *(float4*)(pO + nrow * 128 + kvh * 64 + d) = o;
    }
  }
}

// ---------------- combine partials -> bf16 attn ----------------
__global__ __launch_bounds__(256) void combine_attn(
    const float* __restrict__ pO, const float* __restrict__ pL,
    u16* __restrict__ attn)
{
  const int blk = blockIdx.x;
  const int bh = blk >> 6;
  const int nc = blk & 63;
  const int t = threadIdx.x;
  const int nl = nc * 16 + (t >> 4);
  const int d4 = (t & 15) * 4;
  const size_t n = (size_t)bh * 1024 + nl;
  const float4 a = *(const float4*)(pO + n * 128 + d4);
  const float4 b = *(const float4*)(pO + n * 128 + 64 + d4);
  const float2 ls = *(const float2*)(pL + n * 2);
  const float inv = 1.0f / (ls.x + ls.y);
  ushort4 o;
  o.x = f2bf((a.x + b.x) * inv);
  o.y = f2bf((a.y + b.y) * inv);
  o.z = f2bf((a.z + b.z) * inv);
  o.w = f2bf((a.w + b.w) * inv);
  const int bb = bh >> 3, h = bh & 7;
  *(ushort4*)(attn + (size_t)(bb * 1024 + nl) * 512 + h * 64 + d4) = o;
}

// ---------------- launch ----------------
extern "C" void kernel_launch(void* const* d_in, const int* in_sizes, int n_in,
                              void* d_out, int out_size, void* d_ws, size_t ws_size,
                              hipStream_t stream) {
  const float* x        = (const float*)d_in[0];
  const int*   ids      = (const int*)d_in[1];
  const float* w_qkv    = (const float*)d_in[2];
  const float* w_proj   = (const float*)d_in[3];
  const float* b_proj   = (const float*)d_in[4];
  const float* rel_tab  = (const float*)d_in[5];
  float* out = (float*)d_out;

  char* ws = (char*)d_ws;
  u16* xb   = (u16*)(ws);              // 8192x512 bf16; later reused as attn_out
  u16* wT   = (u16*)(ws + 8388608);    // 1536x512 bf16
  u16* wpT  = (u16*)(ws + 9961472);    // 512x512 bf16
  u16* Qsw  = (u16*)(ws + 10485760);   // swizzled Q, pre-scaled 1/8 (8MB)
  u16* Ksw  = (u16*)(ws + 18874368);   // swizzled K (8MB)
  u16* Vsw  = (u16*)(ws + 27262976);   // sigma-swizzled V (8MB)
  u16* tabb = (u16*)(ws + 35651584);   // bf16 rel_table [16131][8] (258KB)
  float* pO = (float*)(ws + 35913728); // partial O fp32 (33.5MB)
  float* pL = (float*)(ws + 69468160); // partial lsum fp32 (512KB)
  u16* attn = xb;

  cvt_to_bf16<<<4096, 256, 0, stream>>>(x, xb, 8 * 1024 * 512);
  prep_misc<<<1151, 256, 0, stream>>>(w_qkv, w_proj, rel_tab, wT, wpT, tabb);

  gemm_bt<0><<<dim3(64, 8), 256, 0, stream>>>(wT, xb, Qsw, Ksw, nullptr, nullptr);
  gemm_bt<1><<<dim3(4, 64), 256, 0, stream>>>(xb, wT + 1024 * 512, Vsw, nullptr, nullptr, nullptr);

  flash_attn<<<dim3(512), 512, 0, stream>>>(Qsw, Ksw, Vsw, ids, tabb, pO, pL);
  combine_attn<<<dim3(4096), 256, 0, stream>>>(pO, pL, attn);

  gemm_bt<2><<<dim3(64, 4), 256, 0, stream>>>(wpT, attn, nullptr, nullptr, out, b_proj);
}

// Round 17
// 96.210 us; speedup vs baseline: 2.6493x; 1.2952x over previous
//
#include <hip/hip_runtime.h>

typedef __attribute__((ext_vector_type(8))) __bf16 bf16x8;
typedef __attribute__((ext_vector_type(4))) float f32x4;
typedef __attribute__((ext_vector_type(16))) float f32x16;
typedef __attribute__((ext_vector_type(4))) unsigned int u32x4;
typedef unsigned short u16;
typedef unsigned int u32;

__device__ __forceinline__ u16 f2bf(float f) {
  __bf16 h = (__bf16)f;
  return *(u16*)&h;
}
__device__ __forceinline__ float bf2f(u16 h) {
  return __uint_as_float(((u32)h) << 16);
}
__device__ __forceinline__ u32 pack2(float lo, float hi) {
  return (u32)f2bf(lo) | ((u32)f2bf(hi) << 16);
}
__device__ __forceinline__ f32x4 mfma16(bf16x8 a, bf16x8 b, f32x4 c) {
  return __builtin_amdgcn_mfma_f32_16x16x32_bf16(a, b, c, 0, 0, 0);
}
__device__ __forceinline__ f32x16 mfma32(bf16x8 a, bf16x8 b, f32x16 c) {
  return __builtin_amdgcn_mfma_f32_32x32x16_bf16(a, b, c, 0, 0, 0);
}
__device__ __forceinline__ void gl16(const void* g, void* l) {
  __builtin_amdgcn_global_load_lds(
      (const __attribute__((address_space(1))) void*)g,
      (__attribute__((address_space(3))) void*)l, 16, 0, 0);
}

// ---------------- converts ----------------
__global__ void cvt_to_bf16(const float* __restrict__ src, u16* __restrict__ dst, int n) {
  const int i = (blockIdx.x * 256 + threadIdx.x) * 4;
  if (i + 3 < n) {
    const float4 v = *(const float4*)(src + i);
    ushort4 o; o.x = f2bf(v.x); o.y = f2bf(v.y); o.z = f2bf(v.z); o.w = f2bf(v.w);
    *(ushort4*)(dst + i) = o;
  }
}

// fused prep: wqkv^T (blocks 0..767), wproj^T (768..1023), rel_table cvt (1024..1150)
__global__ __launch_bounds__(256) void prep_misc(
    const float* __restrict__ w_qkv, const float* __restrict__ w_proj,
    const float* __restrict__ rel_tab,
    u16* __restrict__ wT, u16* __restrict__ wpT, u16* __restrict__ tabb)
{
  __shared__ float tile[32][33];
  const int b = blockIdx.x;
  const int tid = threadIdx.x;
  if (b < 1024) {
    const float* src; u16* dst; int C, c0, r0;
    if (b < 768) { src = w_qkv; dst = wT; C = 1536; c0 = (b % 48) * 32; r0 = (b / 48) * 32; }
    else { const int bb = b - 768; src = w_proj; dst = wpT; C = 512; c0 = (bb % 16) * 32; r0 = (bb / 16) * 32; }
    const int tx = tid & 31, ty = tid >> 5;
    for (int i = ty; i < 32; i += 8)
      tile[i][tx] = src[(size_t)(r0 + i) * C + c0 + tx];
    __syncthreads();
    for (int i = ty; i < 32; i += 8)
      dst[(size_t)(c0 + i) * 512 + r0 + tx] = f2bf(tile[tx][i]);
  } else {
    const int i = ((b - 1024) * 256 + tid) * 4;
    if (i + 3 < 16131 * 8) {
      const float4 v = *(const float4*)(rel_tab + i);
      ushort4 o; o.x = f2bf(v.x); o.y = f2bf(v.y); o.z = f2bf(v.z); o.w = f2bf(v.w);
      *(ushort4*)(tabb + i) = o;
    }
  }
}

// ---------------- GEMM: C[MxN] = A[Mx512] * Bt[Nx512]^T, K=512 ----------------
template<int MODE>
__global__ __launch_bounds__(256, 2) void gemm_bt(
    const u16* __restrict__ A, const u16* __restrict__ Bt,
    u16* __restrict__ out0, u16* __restrict__ out1,
    float* __restrict__ fout, const float* __restrict__ bias)
{
  __shared__ u16 As[128][32];
  __shared__ u16 Bs[128][32];
  const int tid = threadIdx.x;
  const int w = tid >> 6, l = tid & 63;
  const int lr = l & 15, lg = l >> 4;
  const int wr = w >> 1, wc = w & 1;
  const int m0 = blockIdx.y * 128, n0 = blockIdx.x * 128;
  const int sl = (lr >> 1) & 3;
  const int cA = lg ^ sl;

  f32x4 acc[4][4] = {};

  for (int k0 = 0; k0 < 512; k0 += 32) {
#pragma unroll
    for (int it = 0; it < 2; ++it) {
      const int ch = it * 256 + tid;
      const int row = ch >> 2, cslot = ch & 3;
      const int csrc = cslot ^ ((row >> 1) & 3);
      gl16(A  + (size_t)(m0 + row) * 512 + k0 + csrc * 8, (u16*)As + ch * 8);
      gl16(Bt + (size_t)(n0 + row) * 512 + k0 + csrc * 8, (u16*)Bs + ch * 8);
    }
    __syncthreads();
    bf16x8 af[4], bfr[4];
#pragma unroll
    for (int mi = 0; mi < 4; ++mi)
      af[mi] = *(const bf16x8*)&As[wr * 64 + mi * 16 + lr][cA * 8];
#pragma unroll
    for (int nj = 0; nj < 4; ++nj)
      bfr[nj] = *(const bf16x8*)&Bs[wc * 64 + nj * 16 + lr][cA * 8];
#pragma unroll
    for (int mi = 0; mi < 4; ++mi)
#pragma unroll
      for (int nj = 0; nj < 4; ++nj)
        acc[mi][nj] = mfma16(af[mi], bfr[nj], acc[mi][nj]);
    __syncthreads();
  }

#pragma unroll
  for (int mi = 0; mi < 4; ++mi)
#pragma unroll
    for (int nj = 0; nj < 4; ++nj) {
      const int i0 = m0 + wr * 64 + mi * 16 + lg * 4;
      const int j  = n0 + wc * 64 + nj * 16 + lr;
      if (MODE == 0) {
        const int bb = j >> 10, n = j & 1023;
        const bool isQ = i0 < 512;
        const int f = isQ ? i0 : i0 - 512;
        const int h = f >> 6, d0 = f & 63;
        const float scl = isQ ? 0.125f : 1.0f;
        u16* dst = isQ ? out0 : out1;
        const size_t off = ((size_t)(bb * 8 + h) << 16) +
            ((((n >> 5) * 4 + (d0 >> 4)) * 2 + ((d0 >> 3) & 1)) << 8) +
            ((n & 31) << 3) + (d0 & 7);
        ushort4 o;
        o.x = f2bf(acc[mi][nj][0] * scl); o.y = f2bf(acc[mi][nj][1] * scl);
        o.z = f2bf(acc[mi][nj][2] * scl); o.w = f2bf(acc[mi][nj][3] * scl);
        *(ushort4*)(dst + off) = o;
      } else if (MODE == 1) {
        const int bb = i0 >> 10, m = i0 & 1023;
        const int h = j >> 6, d = j & 63;
        const size_t off = ((size_t)(bb * 8 + h) << 16) +
            ((((m >> 6) * 4 + ((m >> 4) & 3)) * 2 + ((m >> 2) & 1)) << 9) +
            (d << 3) + (((m >> 3) & 1) << 2);
        ushort4 o;
        o.x = f2bf(acc[mi][nj][0]); o.y = f2bf(acc[mi][nj][1]);
        o.z = f2bf(acc[mi][nj][2]); o.w = f2bf(acc[mi][nj][3]);
        *(ushort4*)(out0 + off) = o;
      } else {
        const float4 bp = *(const float4*)(bias + i0);
        float4 o;
        o.x = acc[mi][nj][0] + bp.x; o.y = acc[mi][nj][1] + bp.y;
        o.z = acc[mi][nj][2] + bp.z; o.w = acc[mi][nj][3] + bp.w;
        *(float4*)(fout + (size_t)j * 512 + i0) = o;
      }
    }
}

// ---------------- flash attention (32x32 swapped-operand, sigma-PV, LDS table) ----
// grid 256 (1/CU): bb=bid&7 (XCD chunk), r2=bid>>3: hp=r2&1, g64=r2>>1.
// 512 thr = 8 waves = 4 heads (hp half) x 2 q-subtiles; 16 KV tiles, single pass.
// Bias table HALF (4 heads, 129KB) lives in LDS -> bias gathers are ds_reads,
// bypassing the ~0.25 scattered-miss/cy/CU global-gather ceiling (r12/r15 data).
// Loop is BARRIER-FREE (table read-only): 8 waves run decoupled, no lockstep.
// K and V register double-buffered (256-reg budget at (512,2); ~210 live).
__global__ __launch_bounds__(512, 2) void flash_attn(
    const u16* __restrict__ Qs, const u16* __restrict__ Ks,
    const u16* __restrict__ Vs, const int* __restrict__ ids_keep,
    const u16* __restrict__ tab_bf,
    u16* __restrict__ attn_out)
{
  __shared__ u16 tabL[16129 * 4];   // [idx][4 heads of hp-half], 129 KB
  __shared__ int bofs[1024];        // (8064 - code[m]) * 8  (byte offset step)

  const int bid = blockIdx.x;
  const int bb = bid & 7;
  const int r2 = bid >> 3;
  const int hp = r2 & 1;
  const int g64 = r2 >> 1;
  const int tid = threadIdx.x;
  const int wv = tid >> 6;
  const int hloc = wv & 3;          // head within half
  const int qs = wv >> 2;           // q-subtile 0/1
  const int l = tid & 63, l31 = l & 31, hi5 = l >> 5;
  const int h = hp * 4 + hloc;

  // one-time LDS init: table half + bofs
  for (int e = tid; e < 16129; e += 512)
    *(ushort4*)&tabL[e * 4] = *(const ushort4*)(tab_bf + (size_t)e * 8 + hp * 4);
  for (int e = tid; e < 1024; e += 512) {
    const int id = ids_keep[bb * 1024 + e];
    bofs[e] = (8064 - ((id >> 6) * 127 + (id & 63))) * 8;
  }

  const int nloc = g64 * 64 + qs * 32 + l31;
  const int idn = ids_keep[bb * 1024 + nloc];
  const int base = ((idn >> 6) * 127 + (idn & 63)) * 8 + hloc * 2;  // byte offset

  const size_t hb = (size_t)(bb * 8 + h) << 16;
  const int g32 = g64 * 2 + qs;

  f32x16 acc0 = {}, acc1 = {};
  float lsum = 0.f;

  bf16x8 qf[4];
#pragma unroll
  for (int dch = 0; dch < 4; ++dch)
    qf[dch] = *(const bf16x8*)(Qs + hb + (size_t)(((g32 * 4 + dch) * 2 + hi5) * 256 + l31 * 8));

  auto kload = [&](int t, bf16x8 (&kf)[8]) {
#pragma unroll
    for (int u = 0; u < 2; ++u)
#pragma unroll
      for (int dch = 0; dch < 4; ++dch)
        kf[u * 4 + dch] = *(const bf16x8*)(Ks + hb +
            (size_t)((((2 * t + u) * 4 + dch) * 2 + hi5) * 256 + l31 * 8));
  };
  auto vload = [&](int t, bf16x8 (&vf)[8]) {
#pragma unroll
    for (int cp = 0; cp < 4; ++cp)
#pragma unroll
      for (int dc = 0; dc < 2; ++dc)
        vf[cp * 2 + dc] = *(const bf16x8*)(Vs + hb +
            (size_t)(((t * 4 + cp) * 2 + hi5) * 512 + (dc * 32 + l31) * 8));
  };

  __syncthreads();   // tabL + bofs ready; no barriers after this

  bf16x8 kA[8], kB[8], vA[8], vB[8];
  kload(0, kA);
  vload(0, vA);

  const char* tb = (const char*)tabL;

  auto body = [&](int t, bool pf, bf16x8 (&kC)[8], bf16x8 (&kN)[8],
                  bf16x8 (&vC)[8], bf16x8 (&vN)[8]) {
    if (pf) {
      kload(t + 1, kN);
      vload(t + 1, vN);
    }

    u32 pk[2][4][2];
#pragma unroll
    for (int u = 0; u < 2; ++u) {
      f32x16 s = {};
      s = mfma32(kC[u * 4 + 0], qf[0], s);
      s = mfma32(kC[u * 4 + 1], qf[1], s);
      s = mfma32(kC[u * 4 + 2], qf[2], s);
      s = mfma32(kC[u * 4 + 3], qf[3], s);
#pragma unroll
      for (int a = 0; a < 4; ++a) {
        // m = 32u + 8a + 4*hi5 + r  (verified against 32x32 C-layout)
        const int4 bo = *(const int4*)&bofs[t * 64 + u * 32 + a * 8 + hi5 * 4];
        const float b0 = bf2f(*(const u16*)(tb + base + bo.x));
        const float b1 = bf2f(*(const u16*)(tb + base + bo.y));
        const float b2 = bf2f(*(const u16*)(tb + base + bo.z));
        const float b3 = bf2f(*(const u16*)(tb + base + bo.w));
        float p0 = __expf(s[a * 4 + 0] + b0);
        float p1 = __expf(s[a * 4 + 1] + b1);
        float p2 = __expf(s[a * 4 + 2] + b2);
        float p3 = __expf(s[a * 4 + 3] + b3);
        lsum += (p0 + p1) + (p2 + p3);
        pk[u][a][0] = pack2(p0, p1);
        pk[u][a][1] = pack2(p2, p3);
      }
    }

#pragma unroll
    for (int cp = 0; cp < 4; ++cp) {
      const int u = cp >> 1, cc = cp & 1;
      union { u32x4 u4; bf16x8 v; } pb;
      pb.u4 = (u32x4){pk[u][2 * cc][0], pk[u][2 * cc][1],
                      pk[u][2 * cc + 1][0], pk[u][2 * cc + 1][1]};
      acc0 = mfma32(vC[cp * 2 + 0], pb.v, acc0);
      acc1 = mfma32(vC[cp * 2 + 1], pb.v, acc1);
    }
  };

  for (int tt = 0; tt < 16; tt += 2) {
    body(tt,     tt < 15,     kA, kB, vA, vB);
    body(tt + 1, tt + 1 < 15, kB, kA, vB, vA);
  }

  lsum += __shfl_xor(lsum, 32);
  const float inv = 1.0f / lsum;
  const int nglob = bb * 1024 + nloc;
#pragma unroll
  for (int dc = 0; dc < 2; ++dc) {
    const f32x16& av = dc ? acc1 : acc0;
#pragma unroll
    for (int rq = 0; rq < 4; ++rq) {
      const int d = dc * 32 + rq * 8 + hi5 * 4;
      ushort4 o;
      o.x = f2bf(av[rq * 4 + 0] * inv);
      o.y = f2bf(av[rq * 4 + 1] * inv);
      o.z = f2bf(av[rq * 4 + 2] * inv);
      o.w = f2bf(av[rq * 4 + 3] * inv);
      *(ushort4*)(attn_out + (size_t)nglob * 512 + h * 64 + d) = o;
    }
  }
}

// ---------------- launch ----------------
extern "C" void kernel_launch(void* const* d_in, const int* in_sizes, int n_in,
                              void* d_out, int out_size, void* d_ws, size_t ws_size,
                              hipStream_t stream) {
  const float* x        = (const float*)d_in[0];
  const int*   ids      = (const int*)d_in[1];
  const float* w_qkv    = (const float*)d_in[2];
  const float* w_proj   = (const float*)d_in[3];
  const float* b_proj   = (const float*)d_in[4];
  const float* rel_tab  = (const float*)d_in[5];
  float* out = (float*)d_out;

  char* ws = (char*)d_ws;
  u16* xb   = (u16*)(ws);              // 8192x512 bf16; later reused as attn_out
  u16* wT   = (u16*)(ws + 8388608);    // 1536x512 bf16
  u16* wpT  = (u16*)(ws + 9961472);    // 512x512 bf16
  u16* Qsw  = (u16*)(ws + 10485760);   // swizzled Q, pre-scaled 1/8 (8MB)
  u16* Ksw  = (u16*)(ws + 18874368);   // swizzled K (8MB)
  u16* Vsw  = (u16*)(ws + 27262976);   // sigma-swizzled V (8MB)
  u16* tabb = (u16*)(ws + 35651584);   // bf16 rel_table [16131][8] (258KB)
  u16* attn = xb;

  cvt_to_bf16<<<4096, 256, 0, stream>>>(x, xb, 8 * 1024 * 512);
  prep_misc<<<1151, 256, 0, stream>>>(w_qkv, w_proj, rel_tab, wT, wpT, tabb);

  gemm_bt<0><<<dim3(64, 8), 256, 0, stream>>>(wT, xb, Qsw, Ksw, nullptr, nullptr);
  gemm_bt<1><<<dim3(4, 64), 256, 0, stream>>>(xb, wT + 1024 * 512, Vsw, nullptr, nullptr, nullptr);

  flash_attn<<<dim3(256), 512, 0, stream>>>(Qsw, Ksw, Vsw, ids, tabb, attn);

  gemm_bt<2><<<dim3(64, 4), 256, 0, stream>>>(wpT, attn, nullptr, nullptr, out, b_proj);
}